// Round 1
// baseline (224.344 us; speedup 1.0000x reference)
//
#include <hip/hip_runtime.h>

// KANConv2D: out[b,h,w,f] = conv3x3(x,K)[.,f] + exp(-gamma * d[.,f]) + bias[f]
// d = ||patch||^2 + ||c_f||^2 - 2*patch.c_f ; gamma = (N*F)/(2*sum(d))
//
// Phase plan (all on `stream`):
//  P0: cn[f] = sum_p c[p,f]^2 (fp32), zero the global d-sum accumulator
//  P1: convert+transpose kernel & control_points to bf16 [F][P] in ws
//  P2: s[pix] = sum_c x^2 (fp32)
//  P3: pn[pix] = 3x3 box sum of s (fp32)  == ||patch||^2 exactly
//  D : fused dual implicit-GEMM (bf16 MFMA 16x16x32), writes conv+bias -> d_out,
//      d (bf16) -> ws, atomicAdd(sum d)
//  E : out += exp(-gamma*d)

#define B_ 32
#define H_ 64
#define W_ 64
#define C_ 64
#define F_ 128
#define P_ 576
#define NPIX (B_*H_*W_)          // 131072
#define NF   (NPIX*F_)           // 16777216

typedef __bf16  bf16x8 __attribute__((ext_vector_type(8)));
typedef float   f32x4  __attribute__((ext_vector_type(4)));

__device__ __forceinline__ ushort f2bf(float f) {
    union { float f; unsigned u; } v; v.f = f;
    unsigned u = v.u;
    unsigned r = (u + 0x7fffu + ((u >> 16) & 1u)) >> 16;   // RNE
    return (ushort)r;
}
__device__ __forceinline__ float bf2f(ushort h) {
    union { unsigned u; float f; } v; v.u = ((unsigned)h) << 16;
    return v.f;
}

// ---------------- P0: cn + zero accumulator ----------------
__global__ void k_prep0(const float* __restrict__ ctrl, float* __restrict__ cn,
                        float* __restrict__ accum) {
    int f = threadIdx.x;   // 128 threads
    float s = 0.f;
    for (int p = 0; p < P_; ++p) { float v = ctrl[p * F_ + f]; s += v * v; }
    cn[f] = s;
    if (f == 0) accum[0] = 0.f;
}

// ---------------- P1: convert + transpose both B matrices ----------------
__global__ void k_prep1(const float* __restrict__ wgt, const float* __restrict__ ctrl,
                        ushort* __restrict__ Btw, ushort* __restrict__ Btc) {
    int e = blockIdx.x * 256 + threadIdx.x;   // e < P_*F_ = 73728
    int p = e >> 7, f = e & 127;
    Btw[f * P_ + p] = f2bf(wgt[e]);
    Btc[f * P_ + p] = f2bf(ctrl[e]);
}

// ---------------- P2: per-pixel channel sqnorm ----------------
__global__ void k_sqnorm(const float* __restrict__ in, float* __restrict__ s) {
    int t   = threadIdx.x;
    int pix = blockIdx.x * 16 + (t >> 4);
    int seg = t & 15;
    float4 v = *((const float4*)(in + pix * 64) + seg);
    float x = v.x*v.x + v.y*v.y + v.z*v.z + v.w*v.w;
    x += __shfl_down(x, 8, 16);
    x += __shfl_down(x, 4, 16);
    x += __shfl_down(x, 2, 16);
    x += __shfl_down(x, 1, 16);
    if (seg == 0) s[pix] = x;
}

// ---------------- P3: 3x3 box sum -> patch sqnorm ----------------
__global__ void k_pn(const float* __restrict__ s, float* __restrict__ pn) {
    int n = blockIdx.x * 256 + threadIdx.x;   // < NPIX
    int b = n >> 12, y = (n >> 6) & 63, x = n & 63;
    const float* sb = s + b * 4096;
    float acc = 0.f;
    #pragma unroll
    for (int di = -1; di <= 1; ++di) {
        int yy = y + di; if (yy < 0 || yy >= 64) continue;
        #pragma unroll
        for (int dj = -1; dj <= 1; ++dj) {
            int xx = x + dj; if (xx < 0 || xx >= 64) continue;
            acc += sb[yy * 64 + xx];
        }
    }
    pn[n] = acc;
}

// ---------------- D: fused dual implicit GEMM ----------------
// block = 256 threads (4 waves), tile = 64 rows (one image row) x 128 cols (all F)
// waves 0-1: conv (B = kernel), waves 2-3: dot (B = control). Each wave: 32 rows.
__launch_bounds__(256, 3)
__global__ void k_main(const float* __restrict__ in,
                       const ushort* __restrict__ Btw, const ushort* __restrict__ Btc,
                       const float* __restrict__ bias, const float* __restrict__ cn,
                       const float* __restrict__ pn,
                       float* __restrict__ out, ushort* __restrict__ dws,
                       float* __restrict__ accum) {
    // LDS: A 64x64 bf16 (stride 72), B[2] 128x64 bf16 (stride 72). 46080 B total.
    __shared__ __attribute__((aligned(16))) ushort lA[64 * 72];
    __shared__ __attribute__((aligned(16))) ushort lB[2][128 * 72];

    const int tid  = threadIdx.x;
    const int n0   = blockIdx.x * 64;          // 64 consecutive pixels = 1 image row
    const int b    = n0 >> 12;
    const int y    = (n0 >> 6) & 63;
    const float* inb = in + b * (64 * 64 * 64);

    const int w     = tid >> 6, lane = tid & 63;
    const int mat   = w >> 1;                  // 0: conv, 1: dot
    const int mrow0 = (w & 1) * 32;
    const int quad  = lane >> 4, l16 = lane & 15;

    f32x4 acc[2][8];
    #pragma unroll
    for (int mt = 0; mt < 2; ++mt)
        #pragma unroll
        for (int nt = 0; nt < 8; ++nt)
            acc[mt][nt] = (f32x4){0.f, 0.f, 0.f, 0.f};

    const int ar   = tid >> 4;   // A staging row base (0..15)
    const int aseg = tid & 15;   // float4 segment
    const int bf0  = tid >> 3;   // B staging f base (0..31)
    const int bseg = tid & 7;    // 16B segment

    for (int kc = 0; kc < 9; ++kc) {
        const int ki = kc / 3, kj = kc - 3 * ki;
        const int iy = y + ki - 1;
        const bool rowok = (iy >= 0) && (iy < 64);
        const float* src = inb + iy * 4096;

        __syncthreads();
        // stage A: 64 rows x 64 ch, fp32 -> bf16
        #pragma unroll
        for (int i = 0; i < 4; ++i) {
            int r  = ar + i * 16;
            int ix = r + kj - 1;
            float4 v = make_float4(0.f, 0.f, 0.f, 0.f);
            if (rowok && ix >= 0 && ix < 64)
                v = *(const float4*)(src + ix * 64 + aseg * 4);
            ushort4 o;
            o.x = f2bf(v.x); o.y = f2bf(v.y); o.z = f2bf(v.z); o.w = f2bf(v.w);
            *(ushort4*)&lA[r * 72 + aseg * 4] = o;
        }
        // stage B: both matrices, already bf16 [F][P] in ws (L2-resident)
        #pragma unroll
        for (int m2 = 0; m2 < 2; ++m2) {
            const ushort* Bsrc = (m2 == 0) ? Btw : Btc;
            #pragma unroll
            for (int i = 0; i < 4; ++i) {
                int f = bf0 + i * 32;
                uint4 v = *(const uint4*)(Bsrc + f * P_ + kc * 64 + bseg * 8);
                *(uint4*)&lB[m2][f * 72 + bseg * 8] = v;
            }
        }
        __syncthreads();

        #pragma unroll
        for (int ks = 0; ks < 2; ++ks) {
            const int ko = ks * 32 + quad * 8;
            bf16x8 a0 = *(const bf16x8*)&lA[(mrow0 +      l16) * 72 + ko];
            bf16x8 a1 = *(const bf16x8*)&lA[(mrow0 + 16 + l16) * 72 + ko];
            #pragma unroll
            for (int nt = 0; nt < 8; ++nt) {
                bf16x8 bq = *(const bf16x8*)&lB[mat][(nt * 16 + l16) * 72 + ko];
                acc[0][nt] = __builtin_amdgcn_mfma_f32_16x16x32_bf16(a0, bq, acc[0][nt], 0, 0, 0);
                acc[1][nt] = __builtin_amdgcn_mfma_f32_16x16x32_bf16(a1, bq, acc[1][nt], 0, 0, 0);
            }
        }
    }

    // epilogue — C/D layout: col = lane&15, row = quad*4 + reg  [m89/m91]
    if (mat == 0) {
        float bv[8];
        #pragma unroll
        for (int nt = 0; nt < 8; ++nt) bv[nt] = bias[nt * 16 + l16];
        #pragma unroll
        for (int mt = 0; mt < 2; ++mt) {
            int gmb = n0 + mrow0 + mt * 16 + quad * 4;
            #pragma unroll
            for (int nt = 0; nt < 8; ++nt) {
                int gf = nt * 16 + l16;
                #pragma unroll
                for (int r = 0; r < 4; ++r)
                    out[(gmb + r) * F_ + gf] = acc[mt][nt][r] + bv[nt];
            }
        }
    } else {
        float pv[2][4];
        #pragma unroll
        for (int mt = 0; mt < 2; ++mt)
            #pragma unroll
            for (int r = 0; r < 4; ++r)
                pv[mt][r] = pn[n0 + mrow0 + mt * 16 + quad * 4 + r];
        float cv[8];
        #pragma unroll
        for (int nt = 0; nt < 8; ++nt) cv[nt] = cn[nt * 16 + l16];
        float sum = 0.f;
        #pragma unroll
        for (int mt = 0; mt < 2; ++mt) {
            int gmb = n0 + mrow0 + mt * 16 + quad * 4;
            #pragma unroll
            for (int nt = 0; nt < 8; ++nt) {
                int gf = nt * 16 + l16;
                #pragma unroll
                for (int r = 0; r < 4; ++r) {
                    float dval = pv[mt][r] + cv[nt] - 2.f * acc[mt][nt][r];
                    dws[(gmb + r) * F_ + gf] = f2bf(dval);
                    sum += dval;
                }
            }
        }
        #pragma unroll
        for (int off = 32; off >= 1; off >>= 1) sum += __shfl_down(sum, off, 64);
        if (lane == 0) atomicAdd(accum, sum);
    }
}

// ---------------- E: out += exp(-gamma * d) ----------------
__global__ void k_final(float* __restrict__ out, const ushort* __restrict__ dws,
                        const float* __restrict__ accum) {
    int i = blockIdx.x * 256 + threadIdx.x;       // float4 index, < NF/4
    float gamma = 0.5f * (float)NF / accum[0];    // 1/(2*mean)
    float4 o = ((float4*)out)[i];
    ushort4 d = ((const ushort4*)dws)[i];
    o.x += __expf(-gamma * bf2f(d.x));
    o.y += __expf(-gamma * bf2f(d.y));
    o.z += __expf(-gamma * bf2f(d.z));
    o.w += __expf(-gamma * bf2f(d.w));
    ((float4*)out)[i] = o;
}

extern "C" void kernel_launch(void* const* d_in, const int* in_sizes, int n_in,
                              void* d_out, int out_size, void* d_ws, size_t ws_size,
                              hipStream_t stream) {
    const float* in   = (const float*)d_in[0];   // [32,64,64,64]
    const float* wgt  = (const float*)d_in[1];   // [3,3,64,128]
    const float* bias = (const float*)d_in[2];   // [128]
    const float* ctrl = (const float*)d_in[3];   // [3,3,64,128]
    float* out = (float*)d_out;

    // ws layout (bytes): Btw 0 | Btc 147456 | cn 294912 | accum 295424 |
    //                    s 295440 | pn 819728 | d(bf16) 1344016  (total ~34.9 MB)
    char* ws = (char*)d_ws;
    ushort* Btw   = (ushort*)(ws + 0);
    ushort* Btc   = (ushort*)(ws + 147456);
    float*  cn    = (float*) (ws + 294912);
    float*  accum = (float*) (ws + 295424);
    float*  s     = (float*) (ws + 295440);
    float*  pn    = (float*) (ws + 819728);
    ushort* dws   = (ushort*)(ws + 1344016);

    k_prep0 <<<1,            128, 0, stream>>>(ctrl, cn, accum);
    k_prep1 <<<288,          256, 0, stream>>>(wgt, ctrl, Btw, Btc);
    k_sqnorm<<<NPIX / 16,    256, 0, stream>>>(in, s);
    k_pn    <<<NPIX / 256,   256, 0, stream>>>(s, pn);
    k_main  <<<NPIX / 64,    256, 0, stream>>>(in, Btw, Btc, bias, cn, pn, out, dws, accum);
    k_final <<<NF / 4 / 256, 256, 0, stream>>>(out, dws, accum);
}

// Round 2
// 211.658 us; speedup vs baseline: 1.0599x; 1.0599x over previous
//
#include <hip/hip_runtime.h>

// KANConv2D: out[b,h,w,f] = conv3x3(x,K)[.,f] + exp(-gamma * d[.,f]) + bias[f]
// d = ||patch||^2 + ||c_f||^2 - 2*patch.c_f ; gamma = (N*F)/(2*sum(d))
//
// v2: 512-thread blocks, 128-row x 128-F tile, XOR-swizzled LDS (stride 64),
//     conv(fp16)+d(fp16) packed as uint into d_out, in-place finalize.

#define B_ 32
#define H_ 64
#define W_ 64
#define C_ 64
#define F_ 128
#define P_ 576
#define NPIX (B_*H_*W_)          // 131072
#define NF   (NPIX*F_)           // 16777216

typedef __bf16  bf16x8 __attribute__((ext_vector_type(8)));
typedef float   f32x4  __attribute__((ext_vector_type(4)));

union HU { _Float16 h; ushort u; };

__device__ __forceinline__ ushort f2bf(float f) {
    union { float f; unsigned u; } v; v.f = f;
    unsigned u = v.u;
    return (ushort)((u + 0x7fffu + ((u >> 16) & 1u)) >> 16);   // RNE
}
__device__ __forceinline__ uint pk(float a, float b) {
    return (uint)f2bf(a) | ((uint)f2bf(b) << 16);
}
__device__ __forceinline__ ushort f2h(float f) {
    HU h; h.h = (_Float16)f; return h.u;
}
__device__ __forceinline__ float h2f(ushort u) {
    HU h; h.u = u; return (float)h.h;
}

// ---------------- P0: cn + zero accumulator ----------------
__global__ void k_prep0(const float* __restrict__ ctrl, float* __restrict__ cn,
                        float* __restrict__ accum) {
    int f = threadIdx.x;   // 128 threads
    float s = 0.f;
    for (int p = 0; p < P_; ++p) { float v = ctrl[p * F_ + f]; s += v * v; }
    cn[f] = s;
    if (f == 0) accum[0] = 0.f;
}

// ---------------- P1: convert + transpose both B matrices ----------------
__global__ void k_prep1(const float* __restrict__ wgt, const float* __restrict__ ctrl,
                        ushort* __restrict__ Btw, ushort* __restrict__ Btc) {
    int e = blockIdx.x * 256 + threadIdx.x;   // e < P_*F_ = 73728
    int p = e >> 7, f = e & 127;
    Btw[f * P_ + p] = f2bf(wgt[e]);
    Btc[f * P_ + p] = f2bf(ctrl[e]);
}

// ---------------- P2: per-pixel channel sqnorm ----------------
__global__ void k_sqnorm(const float* __restrict__ in, float* __restrict__ s) {
    int t   = threadIdx.x;
    int pix = blockIdx.x * 16 + (t >> 4);
    int seg = t & 15;
    float4 v = *((const float4*)(in + pix * 64) + seg);
    float x = v.x*v.x + v.y*v.y + v.z*v.z + v.w*v.w;
    x += __shfl_down(x, 8, 16);
    x += __shfl_down(x, 4, 16);
    x += __shfl_down(x, 2, 16);
    x += __shfl_down(x, 1, 16);
    if (seg == 0) s[pix] = x;
}

// ---------------- P3: 3x3 box sum -> patch sqnorm ----------------
__global__ void k_pn(const float* __restrict__ s, float* __restrict__ pn) {
    int n = blockIdx.x * 256 + threadIdx.x;   // < NPIX
    int b = n >> 12, y = (n >> 6) & 63, x = n & 63;
    const float* sb = s + b * 4096;
    float acc = 0.f;
    #pragma unroll
    for (int di = -1; di <= 1; ++di) {
        int yy = y + di; if (yy < 0 || yy >= 64) continue;
        #pragma unroll
        for (int dj = -1; dj <= 1; ++dj) {
            int xx = x + dj; if (xx < 0 || xx >= 64) continue;
            acc += sb[yy * 64 + xx];
        }
    }
    pn[n] = acc;
}

// ---------------- D: fused dual implicit GEMM ----------------
// 512 threads = 8 waves; tile = 128 rows (2 image rows) x 128 F.
// waves 0-3: conv (32 rows each), waves 4-7: dot (32 rows each).
// LDS: A [128][64] bf16 + B [2][128][64] bf16, XOR-swizzled 16B chunks.
// Epilogue: dot waves pass d (fp16) via LDS; conv waves pack (d<<16|conv) -> out.
__launch_bounds__(512, 4)
__global__ void k_main(const float* __restrict__ in,
                       const ushort* __restrict__ Btw, const ushort* __restrict__ Btc,
                       const float* __restrict__ bias, const float* __restrict__ cn,
                       const float* __restrict__ pn,
                       uint* __restrict__ out, float* __restrict__ accum) {
    __shared__ __attribute__((aligned(16))) ushort smem[24576];   // 49152 B
    ushort* lA = smem;            // [128][64] swizzled
    ushort* lB = smem + 8192;     // [2][128][64] swizzled

    const int tid = threadIdx.x;
    const int n0  = blockIdx.x * 128;          // 128 pixels = 2 image rows
    const int b   = n0 >> 12;
    const int y0  = (n0 >> 6) & 63;            // rows y0, y0+1 (same image)
    const float* inb = in + b * (64 * 64 * 64);

    const int w     = tid >> 6, lane = tid & 63;
    const int mat   = w >> 2;                  // 0: conv, 1: dot
    const int mrow0 = (w & 3) * 32;
    const int quad  = lane >> 4, l16 = lane & 15;

    f32x4 acc[2][8];
    #pragma unroll
    for (int mt = 0; mt < 2; ++mt)
        #pragma unroll
        for (int nt = 0; nt < 8; ++nt)
            acc[mt][nt] = (f32x4){0.f, 0.f, 0.f, 0.f};

    for (int kc = 0; kc < 9; ++kc) {
        const int ki = kc / 3, kj = kc - 3 * ki;

        __syncthreads();
        // stage A: 128 rows x 64 ch fp32 -> bf16, 16B/thread/pass x 2 passes
        #pragma unroll
        for (int p = 0; p < 2; ++p) {
            int r  = (tid >> 3) + p * 64;
            int yy = y0 + (r >> 6) + ki - 1;
            int x  = r & 63, ix = x + kj - 1;
            int c  = tid & 7;
            float4 v0 = make_float4(0.f, 0.f, 0.f, 0.f), v1 = v0;
            if (yy >= 0 && yy < 64 && ix >= 0 && ix < 64) {
                const float* sp = inb + yy * 4096 + ix * 64 + c * 8;
                v0 = *(const float4*)sp;
                v1 = *(const float4*)(sp + 4);
            }
            uint4 o = { pk(v0.x, v0.y), pk(v0.z, v0.w), pk(v1.x, v1.y), pk(v1.z, v1.w) };
            *(uint4*)&lA[r * 64 + (((c ^ (r & 7))) << 3)] = o;
        }
        // stage B: both matrices [F][64] bf16 from L2, 4 x 16B/thread
        #pragma unroll
        for (int i = 0; i < 4; ++i) {
            int idx = tid + i * 512;
            int m2 = idx >> 10, f = (idx >> 3) & 127, cc = idx & 7;
            const ushort* src = (m2 ? Btc : Btw) + f * P_ + kc * 64 + cc * 8;
            uint4 v = *(const uint4*)src;
            *(uint4*)&lB[m2 * 8192 + f * 64 + ((cc ^ (f & 7)) << 3)] = v;
        }
        __syncthreads();

        #pragma unroll
        for (int ks = 0; ks < 2; ++ks) {
            const int sw = ((((ks << 2) + quad)) ^ (l16 & 7)) << 3;
            bf16x8 a0 = *(const bf16x8*)&lA[(mrow0 +      l16) * 64 + sw];
            bf16x8 a1 = *(const bf16x8*)&lA[(mrow0 + 16 + l16) * 64 + sw];
            const ushort* lBm = lB + mat * 8192;
            #pragma unroll
            for (int nt = 0; nt < 8; ++nt) {
                bf16x8 bq = *(const bf16x8*)&lBm[(nt * 16 + l16) * 64 + sw];
                acc[0][nt] = __builtin_amdgcn_mfma_f32_16x16x32_bf16(a0, bq, acc[0][nt], 0, 0, 0);
                acc[1][nt] = __builtin_amdgcn_mfma_f32_16x16x32_bf16(a1, bq, acc[1][nt], 0, 0, 0);
            }
        }
    }

    // ---- epilogue: C/D layout col=lane&15, row=quad*4+reg [m89/m91] ----
    // exchange region: slot per (wave&3, lane), stride 68 ushorts (8B-aligned)
    ushort* exch = smem;
    __syncthreads();
    if (mat == 1) {
        float pv[2][4];
        #pragma unroll
        for (int mt = 0; mt < 2; ++mt)
            #pragma unroll
            for (int r = 0; r < 4; ++r)
                pv[mt][r] = pn[n0 + mrow0 + mt * 16 + quad * 4 + r];
        float cv[8];
        #pragma unroll
        for (int nt = 0; nt < 8; ++nt) cv[nt] = cn[nt * 16 + l16];
        float sum = 0.f;
        ushort* my = exch + ((w & 3) * 64 + lane) * 68;
        #pragma unroll
        for (int mt = 0; mt < 2; ++mt)
            #pragma unroll
            for (int nt = 0; nt < 8; ++nt) {
                ushort4 hv;
                float d0 = pv[mt][0] + cv[nt] - 2.f * acc[mt][nt][0];
                float d1 = pv[mt][1] + cv[nt] - 2.f * acc[mt][nt][1];
                float d2 = pv[mt][2] + cv[nt] - 2.f * acc[mt][nt][2];
                float d3 = pv[mt][3] + cv[nt] - 2.f * acc[mt][nt][3];
                sum += d0 + d1 + d2 + d3;
                hv.x = f2h(d0); hv.y = f2h(d1); hv.z = f2h(d2); hv.w = f2h(d3);
                *(ushort4*)&my[(mt * 8 + nt) * 4] = hv;
            }
        #pragma unroll
        for (int off = 32; off >= 1; off >>= 1) sum += __shfl_down(sum, off, 64);
        if (lane == 0) atomicAdd(accum, sum);
    }
    __syncthreads();
    if (mat == 0) {
        float bv[8];
        #pragma unroll
        for (int nt = 0; nt < 8; ++nt) bv[nt] = bias[nt * 16 + l16];
        const ushort* my = exch + ((w & 3) * 64 + lane) * 68;
        #pragma unroll
        for (int mt = 0; mt < 2; ++mt) {
            int gmb = n0 + mrow0 + mt * 16 + quad * 4;
            #pragma unroll
            for (int nt = 0; nt < 8; ++nt) {
                int gf = nt * 16 + l16;
                ushort4 hv = *(const ushort4*)&my[(mt * 8 + nt) * 4];
                ushort dd[4] = { hv.x, hv.y, hv.z, hv.w };
                #pragma unroll
                for (int r = 0; r < 4; ++r) {
                    uint pkv = ((uint)dd[r] << 16) | (uint)f2h(acc[mt][nt][r] + bv[nt]);
                    out[(gmb + r) * F_ + gf] = pkv;
                }
            }
        }
    }
}

// ---------------- E: in-place out = conv + exp(-gamma*d) ----------------
__global__ void k_final(uint* __restrict__ out, const float* __restrict__ accum) {
    int i = blockIdx.x * 256 + threadIdx.x;       // handles elems [8i, 8i+8)
    float g = 0.5f * (float)NF / accum[0];        // gamma = 1/(2*mean)
    uint4* p = (uint4*)out;
    uint4 u0 = p[2 * i], u1 = p[2 * i + 1];
    float4 f0, f1;
    f0.x = h2f((ushort)(u0.x & 0xffff)) + __expf(-g * h2f((ushort)(u0.x >> 16)));
    f0.y = h2f((ushort)(u0.y & 0xffff)) + __expf(-g * h2f((ushort)(u0.y >> 16)));
    f0.z = h2f((ushort)(u0.z & 0xffff)) + __expf(-g * h2f((ushort)(u0.z >> 16)));
    f0.w = h2f((ushort)(u0.w & 0xffff)) + __expf(-g * h2f((ushort)(u0.w >> 16)));
    f1.x = h2f((ushort)(u1.x & 0xffff)) + __expf(-g * h2f((ushort)(u1.x >> 16)));
    f1.y = h2f((ushort)(u1.y & 0xffff)) + __expf(-g * h2f((ushort)(u1.y >> 16)));
    f1.z = h2f((ushort)(u1.z & 0xffff)) + __expf(-g * h2f((ushort)(u1.z >> 16)));
    f1.w = h2f((ushort)(u1.w & 0xffff)) + __expf(-g * h2f((ushort)(u1.w >> 16)));
    float4* q = (float4*)out;
    q[2 * i] = f0; q[2 * i + 1] = f1;             // in-place, same bytes
}

extern "C" void kernel_launch(void* const* d_in, const int* in_sizes, int n_in,
                              void* d_out, int out_size, void* d_ws, size_t ws_size,
                              hipStream_t stream) {
    const float* in   = (const float*)d_in[0];   // [32,64,64,64]
    const float* wgt  = (const float*)d_in[1];   // [3,3,64,128]
    const float* bias = (const float*)d_in[2];   // [128]
    const float* ctrl = (const float*)d_in[3];   // [3,3,64,128]
    uint* out = (uint*)d_out;

    // ws layout (bytes): Btw 0 | Btc 147456 | cn 294912 | accum 295424 |
    //                    s 295440 | pn 819728   (total ~1.35 MB)
    char* ws = (char*)d_ws;
    ushort* Btw   = (ushort*)(ws + 0);
    ushort* Btc   = (ushort*)(ws + 147456);
    float*  cn    = (float*) (ws + 294912);
    float*  accum = (float*) (ws + 295424);
    float*  s     = (float*) (ws + 295440);
    float*  pn    = (float*) (ws + 819728);

    k_prep0 <<<1,            128, 0, stream>>>(ctrl, cn, accum);
    k_prep1 <<<288,          256, 0, stream>>>(wgt, ctrl, Btw, Btc);
    k_sqnorm<<<NPIX / 16,    256, 0, stream>>>(in, s);
    k_pn    <<<NPIX / 256,   256, 0, stream>>>(s, pn);
    k_main  <<<NPIX / 128,   512, 0, stream>>>(in, Btw, Btc, bias, cn, pn, out, accum);
    k_final <<<NF / 8 / 256, 256, 0, stream>>>(out, accum);
}